// Round 1
// baseline (45.781 us; speedup 1.0000x reference)
//
#include <hip/hip_runtime.h>

#define NTYPES 100
#define EMBED 64
#define N_BATCH 9000
#define ATOMS_PER_MOL 64
#define N_ATOMS (N_BATCH * ATOMS_PER_MOL)   // 576000

// ---------------------------------------------------------------------------
// Kernel 1: zero the presence array (128 ints in d_ws; ws is poisoned 0xAA
// and never re-poisoned, so we must clear it every call).
// ---------------------------------------------------------------------------
__global__ void ae_zero_present(int* __restrict__ present) {
    if (threadIdx.x < 128) present[threadIdx.x] = 0;
}

// ---------------------------------------------------------------------------
// Kernel 2: mark which atom types occur. Plain stores of 1 — races between
// blocks write the same value, which is benign. int4 vectorized loads.
// ---------------------------------------------------------------------------
__global__ void ae_mark_present(const int4* __restrict__ at4,
                                int* __restrict__ present, int n4) {
    int stride = gridDim.x * blockDim.x;
    for (int i = blockIdx.x * blockDim.x + threadIdx.x; i < n4; i += stride) {
        int4 v = at4[i];
        present[v.x] = 1;
        present[v.y] = 1;
        present[v.z] = 1;
        present[v.w] = 1;
    }
}

// ---------------------------------------------------------------------------
// Kernel 3 (1 block, 256 threads): rank[t] = #present types < t
// (== searchsorted(uniq, t) for t present), then build the remapped table
// remap[t][d] = embedding[rank[t]][d]. For absent t the entry is never read
// by the gather; rank[t] <= 99 always, so no OOB.
// ---------------------------------------------------------------------------
__global__ void ae_build_remap(const int* __restrict__ present,
                               const float* __restrict__ embedding,
                               float* __restrict__ remap) {
    __shared__ int s_present[NTYPES];
    __shared__ int s_rank[NTYPES];
    int tid = threadIdx.x;
    if (tid < NTYPES) s_present[tid] = present[tid];
    __syncthreads();
    if (tid < NTYPES) {
        int r = 0;
        for (int j = 0; j < tid; ++j) r += s_present[j];
        s_rank[tid] = r;
    }
    __syncthreads();
    for (int idx = tid; idx < NTYPES * EMBED; idx += blockDim.x) {
        int t = idx >> 6;      // / EMBED
        int d = idx & 63;      // % EMBED
        remap[idx] = embedding[s_rank[t] * EMBED + d];
    }
}

// ---------------------------------------------------------------------------
// Kernel 4 (hot): 16 threads per atom; thread q of atom i copies float4 #q of
// the atom's 64-float embedding row. Stores: 16 B/lane, fully coalesced.
// Each 16-lane group reads 256 contiguous bytes of the 25.6 KB remap table
// (L1/L2-resident). atom_types read is broadcast within each 16-lane group.
// ---------------------------------------------------------------------------
__global__ void ae_gather(const int* __restrict__ atom_types,
                          const float4* __restrict__ remap4,
                          float4* __restrict__ out4, int total) {
    int stride = gridDim.x * blockDim.x;
    for (int g = blockIdx.x * blockDim.x + threadIdx.x; g < total; g += stride) {
        int i = g >> 4;        // atom index
        int q = g & 15;        // float4 index within the 64-float row
        int t = atom_types[i];
        out4[g] = remap4[t * 16 + q];
    }
}

extern "C" void kernel_launch(void* const* d_in, const int* in_sizes, int n_in,
                              void* d_out, int out_size, void* d_ws, size_t ws_size,
                              hipStream_t stream) {
    const int* atom_types    = (const int*)d_in[0];    // [9000,64] int32
    const float* embedding   = (const float*)d_in[1];  // [100,64]  f32
    float* out               = (float*)d_out;          // [9000,64,64] f32

    // Workspace layout:
    //   [0,   512)  : int present[128]
    //   [512, 512+NTYPES*EMBED*4) : float remap[100][64]  (25600 B)
    int*   present = (int*)d_ws;
    float* remap   = (float*)((char*)d_ws + 512);

    ae_zero_present<<<1, 128, 0, stream>>>(present);

    int n4 = N_ATOMS / 4;  // 144000 int4 loads
    ae_mark_present<<<1024, 256, 0, stream>>>((const int4*)atom_types, present, n4);

    ae_build_remap<<<1, 256, 0, stream>>>(present, embedding, remap);

    int total = N_ATOMS * 16;  // 9,216,000 float4 stores
    ae_gather<<<2048, 256, 0, stream>>>(atom_types, (const float4*)remap,
                                        (float4*)out, total);
}

// Round 2
// 38.570 us; speedup vs baseline: 1.1870x; 1.1870x over previous
//
#include <hip/hip_runtime.h>

#define NTYPES 100
#define EMBED 64
#define N_BATCH 9000
#define ATOMS_PER_MOL 64
#define N_ATOMS (N_BATCH * ATOMS_PER_MOL)   // 576000
#define TOTAL4 (N_ATOMS * 16)               // 9,216,000 float4 outputs

// ---------------------------------------------------------------------------
// Kernel 1: mark which atom types occur. Plain stores of 1 — cross-block
// races write the same value, benign. int4 vectorized loads, exact-cover grid.
// Presence array was zeroed by a hipMemsetAsync node before this dispatch.
// ---------------------------------------------------------------------------
__global__ void ae_mark_present(const int4* __restrict__ at4,
                                int* __restrict__ present, int n4) {
    int i = blockIdx.x * blockDim.x + threadIdx.x;
    if (i < n4) {
        int4 v = at4[i];
        present[v.x] = 1;
        present[v.y] = 1;
        present[v.z] = 1;
        present[v.w] = 1;
    }
}

// ---------------------------------------------------------------------------
// Kernel 2 (hot, fused rank+gather): each block first computes
// rank[t] = #present types < t  (== searchsorted(uniq, t) for present t)
// into LDS (400 B read, O(100) scan — amortized over ~4480 iters/block),
// then gathers embedding[rank[t]] rows.
//   - 16 threads per atom; thread q writes float4 #q of the 64-float row:
//     stores are 16 B/lane fully coalesced (1 KB/wave/instr).
//   - embedding table is 25.6 KB -> L1/L2 resident; each 16-lane group reads
//     256 contiguous bytes.
//   - absent types get a collapsed rank that is never read -> always <100,
//     no OOB.
// ---------------------------------------------------------------------------
__global__ __launch_bounds__(256) void ae_gather(
        const int* __restrict__ atom_types,
        const float4* __restrict__ emb4,
        const int* __restrict__ present,
        float4* __restrict__ out4) {
    __shared__ int s_present[NTYPES];
    __shared__ int s_rank[NTYPES];
    int tid = threadIdx.x;
    if (tid < NTYPES) s_present[tid] = present[tid];
    __syncthreads();
    if (tid < NTYPES) {
        int r = 0;
        for (int j = 0; j < tid; ++j) r += s_present[j];
        s_rank[tid] = r;
    }
    __syncthreads();

    int stride = gridDim.x * blockDim.x;
    for (int g = blockIdx.x * blockDim.x + tid; g < TOTAL4; g += stride) {
        int t = atom_types[g >> 4];         // broadcast within 16-lane group
        int r = s_rank[t];                  // LDS, ≤4 distinct addrs/wave
        out4[g] = emb4[r * 16 + (g & 15)];  // L1-resident read, coalesced store
    }
}

extern "C" void kernel_launch(void* const* d_in, const int* in_sizes, int n_in,
                              void* d_out, int out_size, void* d_ws, size_t ws_size,
                              hipStream_t stream) {
    const int* atom_types  = (const int*)d_in[0];    // [9000,64] int32
    const float* embedding = (const float*)d_in[1];  // [100,64]  f32
    float* out             = (float*)d_out;          // [9000,64,64] f32

    int* present = (int*)d_ws;  // 128 ints

    // Dispatch 0: zero presence flags (ws is poisoned 0xAA; memset node is
    // graph-capture legal and cheaper than a 1-block kernel).
    hipMemsetAsync(present, 0, 512, stream);

    // Dispatch 1: presence marking. 144000 int4 items, exact-cover grid.
    int n4 = N_ATOMS / 4;
    ae_mark_present<<<(n4 + 255) / 256, 256, 0, stream>>>(
        (const int4*)atom_types, present, n4);

    // Dispatch 2: fused rank + gather.
    ae_gather<<<2048, 256, 0, stream>>>(atom_types, (const float4*)embedding,
                                        present, (float4*)out);
}